// Round 4
// baseline (116.792 us; speedup 1.0000x reference)
//
#include <hip/hip_runtime.h>
#include <cfloat>

// Problem constants (fixed by reference): B=4, N=M=8192, D=3, fp32.
#define BB    4
#define NN    8192
#define MM    8192
#define NPTS  (BB * NN)      // 32768 points per tensor
#define QT    8              // queries per thread (register tile)
#define QB    (256 * QT)     // 2048 queries per block
#define QBLKS (NPTS / QB)    // 16 query-blocks per direction
#define CH    32             // target chunks per direction
#define CHUNK (MM / CH)      // 256 targets per chunk (4 KB LDS paired layout)

typedef float f32x2 __attribute__((ext_vector_type(2)));

// d = a * b + c per 32-bit half. v_pk_fma_f32 needs ALL operands as
// even-aligned VGPR pairs (it is a true 64-bit packed op) — scalar
// broadcast is done by pre-duplicating into both halves of `a`.
__device__ __forceinline__ f32x2 pk_fma(f32x2 a, f32x2 b, f32x2 c) {
    f32x2 d;
    asm("v_pk_fma_f32 %0, %1, %2, %3"
        : "=v"(d) : "v"(a), "v"(b), "v"(c));
    return d;
}

// Monotone float->uint mapping so uint atomicMin == float min (handles negatives).
__device__ __forceinline__ unsigned int fmap(float f) {
    unsigned int u = __float_as_uint(f);
    return (u & 0x80000000u) ? ~u : (u | 0x80000000u);
}
__device__ __forceinline__ float funmap(unsigned int u) {
    u = (u & 0x80000000u) ? (u & 0x7FFFFFFFu) : ~u;
    return __uint_as_float(u);
}

// Each thread: QT=8 query points vs a CHUNK of targets staged in LDS in
// paired layout (x0,x1)(y0,y1)(z0,z1)(w0,w1), w = ||t||^2.
// Tracks m = min_j( ||t||^2 - 2 q.t ); reduce adds ||q||^2.
// Inner: per 2 targets per query = 3 v_pk_fma_f32 + 1 v_min3_f32.
__global__ void __launch_bounds__(256, 4) chamfer_main(
        const float* __restrict__ gts, const float* __restrict__ preds,
        unsigned int* __restrict__ mins) {
    __shared__ float sb[CHUNK * 4];

    int bid  = blockIdx.x;          // grid = 2 * QBLKS * CH = 1024
    int dir  = bid >> 9;            // 512 blocks per direction
    int bi   = bid & 511;
    int pblk = bi & (QBLKS - 1);    // 16 query-blocks
    int ch   = bi >> 4;             // 32 chunks
    int b    = (pblk * QB) >> 13;   // batch index, uniform per block

    const float* __restrict__ Q = dir ? preds : gts;
    const float* __restrict__ T = dir ? gts : preds;
    const float* __restrict__ tc = T + (size_t)(b * MM + ch * CHUNK) * 3;

    // Stage chunk: thread t packs target t into paired layout, w computed here.
    {
        int t = threadIdx.x;        // CHUNK == blockDim == 256
        float x = tc[3 * t + 0], y = tc[3 * t + 1], z = tc[3 * t + 2];
        float w = fmaf(x, x, fmaf(y, y, z * z));
        int p = t >> 1, h = t & 1;
        sb[8 * p + 0 + h] = x;
        sb[8 * p + 2 + h] = y;
        sb[8 * p + 4 + h] = z;
        sb[8 * p + 6 + h] = w;
    }

    int qbase = pblk * QB + threadIdx.x;
    f32x2 nqx[QT], nqy[QT], nqz[QT];
    float m[QT];
    #pragma unroll
    for (int k = 0; k < QT; ++k) {
        const float* qp = Q + (size_t)(qbase + 256 * k) * 3;
        float ax = -2.0f * qp[0], ay = -2.0f * qp[1], az = -2.0f * qp[2];
        nqx[k] = (f32x2){ax, ax};
        nqy[k] = (f32x2){ay, ay};
        nqz[k] = (f32x2){az, az};
        m[k] = FLT_MAX;
    }
    __syncthreads();

    const f32x2* __restrict__ s2 = (const f32x2*)sb;
    #pragma unroll 4
    for (int p = 0; p < CHUNK / 2; ++p) {
        f32x2 x01 = s2[4 * p + 0];   // adjacent -> ds_read_b128 x2 per step
        f32x2 y01 = s2[4 * p + 1];
        f32x2 z01 = s2[4 * p + 2];
        f32x2 w01 = s2[4 * p + 3];
        #pragma unroll
        for (int k = 0; k < QT; ++k) {
            f32x2 s = pk_fma(nqx[k], x01, w01);
            s = pk_fma(nqy[k], y01, s);
            s = pk_fma(nqz[k], z01, s);
            m[k] = fminf(m[k], fminf(s[0], s[1]));   // folds to v_min3_f32
        }
    }

    #pragma unroll
    for (int k = 0; k < QT; ++k)
        atomicMin(&mins[dir * NPTS + qbase + 256 * k], fmap(m[k]));
}

// Sum over all points: unmap(min) + ||q||^2 ; block reduce; one atomicAdd.
__global__ void chamfer_reduce(const unsigned int* __restrict__ mins,
                               const float* __restrict__ gts,
                               const float* __restrict__ preds,
                               float* __restrict__ out) {
    int g = blockIdx.x * blockDim.x + threadIdx.x;   // 0 .. 2*NPTS-1
    const float* p = (g < NPTS) ? (gts + (size_t)g * 3)
                                : (preds + (size_t)(g - NPTS) * 3);
    float x = p[0], y = p[1], z = p[2];
    float val = funmap(mins[g]) + fmaf(x, x, fmaf(y, y, z * z));

    #pragma unroll
    for (int off = 32; off > 0; off >>= 1)
        val += __shfl_down(val, off, 64);

    __shared__ float s[4];
    int lane = threadIdx.x & 63;
    int w_id = threadIdx.x >> 6;
    if (lane == 0) s[w_id] = val;
    __syncthreads();
    if (threadIdx.x == 0)
        atomicAdd(out, s[0] + s[1] + s[2] + s[3]);
}

extern "C" void kernel_launch(void* const* d_in, const int* in_sizes, int n_in,
                              void* d_out, int out_size, void* d_ws, size_t ws_size,
                              hipStream_t stream) {
    const float* gts   = (const float*)d_in[0];
    const float* preds = (const float*)d_in[1];
    float* out = (float*)d_out;

    unsigned int* mins = (unsigned int*)d_ws;        // 256 KB

    hipMemsetAsync(mins, 0xFF, (size_t)2 * NPTS * sizeof(unsigned int), stream);
    hipMemsetAsync(out, 0, (size_t)out_size * sizeof(float), stream);
    chamfer_main  <<<2 * QBLKS * CH, 256, 0, stream>>>(gts, preds, mins);
    chamfer_reduce<<<(2 * NPTS) / 256, 256, 0, stream>>>(mins, gts, preds, out);
}

// Round 5
// 106.770 us; speedup vs baseline: 1.0939x; 1.0939x over previous
//
#include <hip/hip_runtime.h>
#include <cfloat>

// Problem constants (fixed by reference): B=4, N=M=8192, D=3, fp32.
#define BB    4
#define NN    8192
#define MM    8192
#define NPTS  (BB * NN)      // 32768 points per tensor
#define QT    8              // queries per thread (register tile)
#define QB    (256 * QT)     // 2048 queries per block
#define QBLKS (NPTS / QB)    // 16 query-blocks per direction
#define CH    64             // target chunks per direction
#define CHUNK (MM / CH)      // 128 targets per chunk (2 KB LDS paired layout)

typedef float f32x2 __attribute__((ext_vector_type(2)));

// Packed fp32 fma: compiler selects v_pk_fma_f32 (gfx90a+) from llvm.fma.v2f32.
// NO inline asm — asm-constrained pairs forced v_mov marshaling in R4 (3x instrs).
__device__ __forceinline__ f32x2 pk_fma(f32x2 a, f32x2 b, f32x2 c) {
#if __has_builtin(__builtin_elementwise_fma)
    return __builtin_elementwise_fma(a, b, c);
#else
    f32x2 d; d.x = fmaf(a.x, b.x, c.x); d.y = fmaf(a.y, b.y, c.y); return d;
#endif
}

// Monotone float->uint mapping so uint atomicMin == float min (handles negatives).
__device__ __forceinline__ unsigned int fmap(float f) {
    unsigned int u = __float_as_uint(f);
    return (u & 0x80000000u) ? ~u : (u | 0x80000000u);
}
__device__ __forceinline__ float funmap(unsigned int u) {
    u = (u & 0x80000000u) ? (u & 0x7FFFFFFFu) : ~u;
    return __uint_as_float(u);
}

// Each thread: QT=8 query points vs a CHUNK of targets staged in LDS in
// paired layout (x0,x1)(y0,y1)(z0,z1)(w0,w1), w = ||t||^2.
// Tracks m = min_j( ||t||^2 - 2 q.t ); reduce adds ||q||^2.
// Inner: per 2 targets per query = 3 v_pk_fma_f32 + 1 v_min3_f32.
__global__ void __launch_bounds__(256, 4) chamfer_main(
        const float* __restrict__ gts, const float* __restrict__ preds,
        unsigned int* __restrict__ mins) {
    __shared__ float sb[CHUNK * 4];

    int bid  = blockIdx.x;          // grid = 2 * QBLKS * CH = 2048
    int dir  = bid >> 10;           // 1024 blocks per direction
    int bi   = bid & 1023;
    int pblk = bi & (QBLKS - 1);    // 16 query-blocks
    int ch   = bi >> 4;             // 64 chunks
    int b    = pblk >> 2;           // batch index (QB=2048, 4 qblocks/batch)

    const float* __restrict__ Q = dir ? preds : gts;
    const float* __restrict__ T = dir ? gts : preds;
    const float* __restrict__ tc = T + (size_t)(b * MM + ch * CHUNK) * 3;

    // Stage chunk (threads 0..CHUNK-1): pack target t into paired layout.
    if (threadIdx.x < CHUNK) {
        int t = threadIdx.x;
        float x = tc[3 * t + 0], y = tc[3 * t + 1], z = tc[3 * t + 2];
        float w = fmaf(x, x, fmaf(y, y, z * z));
        int p = t >> 1, h = t & 1;
        sb[8 * p + 0 + h] = x;
        sb[8 * p + 2 + h] = y;
        sb[8 * p + 4 + h] = z;
        sb[8 * p + 6 + h] = w;
    }

    int qbase = pblk * QB + threadIdx.x;
    f32x2 nqx[QT], nqy[QT], nqz[QT];
    float m[QT];
    #pragma unroll
    for (int k = 0; k < QT; ++k) {
        const float* qp = Q + (size_t)(qbase + 256 * k) * 3;
        float ax = -2.0f * qp[0], ay = -2.0f * qp[1], az = -2.0f * qp[2];
        nqx[k] = (f32x2){ax, ax};
        nqy[k] = (f32x2){ay, ay};
        nqz[k] = (f32x2){az, az};
        m[k] = FLT_MAX;
    }
    __syncthreads();

    const f32x2* __restrict__ s2 = (const f32x2*)sb;
    #pragma unroll 4
    for (int p = 0; p < CHUNK / 2; ++p) {
        f32x2 x01 = s2[4 * p + 0];
        f32x2 y01 = s2[4 * p + 1];
        f32x2 z01 = s2[4 * p + 2];
        f32x2 w01 = s2[4 * p + 3];
        #pragma unroll
        for (int k = 0; k < QT; ++k) {
            f32x2 s = pk_fma(nqx[k], x01, w01);
            s = pk_fma(nqy[k], y01, s);
            s = pk_fma(nqz[k], z01, s);
            m[k] = fminf(m[k], fminf(s.x, s.y));   // folds to v_min3_f32
        }
    }

    #pragma unroll
    for (int k = 0; k < QT; ++k)
        atomicMin(&mins[dir * NPTS + qbase + 256 * k], fmap(m[k]));
}

// Sum over all points: unmap(min) + ||q||^2 ; block reduce; one atomicAdd.
__global__ void chamfer_reduce(const unsigned int* __restrict__ mins,
                               const float* __restrict__ gts,
                               const float* __restrict__ preds,
                               float* __restrict__ out) {
    int g = blockIdx.x * blockDim.x + threadIdx.x;   // 0 .. 2*NPTS-1
    const float* p = (g < NPTS) ? (gts + (size_t)g * 3)
                                : (preds + (size_t)(g - NPTS) * 3);
    float x = p[0], y = p[1], z = p[2];
    float val = funmap(mins[g]) + fmaf(x, x, fmaf(y, y, z * z));

    #pragma unroll
    for (int off = 32; off > 0; off >>= 1)
        val += __shfl_down(val, off, 64);

    __shared__ float s[4];
    int lane = threadIdx.x & 63;
    int w_id = threadIdx.x >> 6;
    if (lane == 0) s[w_id] = val;
    __syncthreads();
    if (threadIdx.x == 0)
        atomicAdd(out, s[0] + s[1] + s[2] + s[3]);
}

extern "C" void kernel_launch(void* const* d_in, const int* in_sizes, int n_in,
                              void* d_out, int out_size, void* d_ws, size_t ws_size,
                              hipStream_t stream) {
    const float* gts   = (const float*)d_in[0];
    const float* preds = (const float*)d_in[1];
    float* out = (float*)d_out;

    unsigned int* mins = (unsigned int*)d_ws;        // 256 KB

    hipMemsetAsync(mins, 0xFF, (size_t)2 * NPTS * sizeof(unsigned int), stream);
    hipMemsetAsync(out, 0, (size_t)out_size * sizeof(float), stream);
    chamfer_main  <<<2 * QBLKS * CH, 256, 0, stream>>>(gts, preds, mins);
    chamfer_reduce<<<(2 * NPTS) / 256, 256, 0, stream>>>(mins, gts, preds, out);
}